// Round 1
// baseline (748.613 us; speedup 1.0000x reference)
//
#include <hip/hip_runtime.h>

// Problem constants (match reference)
#define C 8            // NUM_CHIPS
#define S 2048         // SEQ
#define H 1024         // HIDDEN
#define K 8            // TOPK
#define E 64           // N_ROUTED_EXPERTS
#define MT 2560        // MAX_TOK
#define ML 8           // METADATA_LEN
#define N (S * K)      // assignments per chip = 16384
#define SEG 256        // assignments per histogram segment
#define NSEG (N / SEG) // 64 segments per chip
#define DISP_ELEMS ((long long)E * MT * H)   // 167,772,160
#define META_ELEMS ((long long)E * MT * ML)  // 1,310,720

// ---------------------------------------------------------------------------
// K1: per-(chip,segment) expert histogram. blockIdx = c*NSEG + seg.
// Note b*SEG == c*N + seg*SEG, so idx indexing is just b*SEG + tid.
__global__ void hist_kernel(const int* __restrict__ idx, int* __restrict__ seg_counts) {
    __shared__ int hist[E];
    const int b = blockIdx.x;
    const int t = threadIdx.x;
    if (t < E) hist[t] = 0;
    __syncthreads();
    const int e = idx[b * SEG + t];
    atomicAdd(&hist[e], 1);
    __syncthreads();
    if (t < E) seg_counts[b * E + t] = hist[t];
}

// ---------------------------------------------------------------------------
// K2: serial prefix over (chip, seg) per expert. Since the scan order is
// chip-major then segment, the running prefix IS chip_offset + within-chip
// prefix from the reference. 1 block, 64 threads (one wave), coalesced reads.
__global__ void scan_kernel(const int* __restrict__ seg_counts,
                            int* __restrict__ seg_base,
                            int* __restrict__ tokens_total,
                            float* __restrict__ tpe_out) {
    const int e = threadIdx.x; // 0..63
    int running = 0;
    for (int cs = 0; cs < C * NSEG; ++cs) {
        seg_base[cs * E + e] = running;
        running += seg_counts[cs * E + e];
    }
    tokens_total[e] = running;
    tpe_out[e] = (float)running; // third output (counts as numeric values)
}

// ---------------------------------------------------------------------------
// K3: stable within-segment rank + final destination slot.
__global__ void rank_kernel(const int* __restrict__ idx,
                            const int* __restrict__ seg_base,
                            int* __restrict__ dest) {
    __shared__ int se[SEG];
    const int b = blockIdx.x;
    const int t = threadIdx.x;
    const int e = idx[b * SEG + t];
    se[t] = e;
    __syncthreads();
    int rank = 0;
    for (int j = 0; j < t; ++j) rank += (se[j] == e);
    dest[b * SEG + t] = e * MT + seg_base[b * E + e] + rank;
}

// ---------------------------------------------------------------------------
// K4: scatter. One block per (chip, token): read the 4KB row once, write it
// to its 8 destination rows (each a fully coalesced 4KB burst) + metadata.
__global__ void scatter_kernel(const float* __restrict__ x,
                               const float* __restrict__ w,
                               const int* __restrict__ dest,
                               float* __restrict__ out) {
    __shared__ int d8[K];
    __shared__ float w8[K];
    const int b = blockIdx.x;       // c*S + tok
    const int t = threadIdx.x;      // 0..255
    const int c = b >> 11;          // / S
    const int tok = b & (S - 1);
    if (t < K) {
        d8[t] = dest[c * N + tok * K + t];
        w8[t] = w[b * K + t];
    }
    __syncthreads();

    const float4 v = ((const float4*)x)[(long long)b * (H / 4) + t];
    float4* o4 = (float4*)out;
#pragma unroll
    for (int k = 0; k < K; ++k) {
        o4[(long long)d8[k] * (H / 4) + t] = v;
    }

    // metadata rows: [chip, token, topk, expert, weight, 0, 0, 0]
    float* meta = out + DISP_ELEMS;
    if (t < K * ML) {
        const int k = t >> 3;
        const int j = t & 7;
        const int d = d8[k];
        float val = 0.0f;
        if (j == 0) val = (float)c;
        else if (j == 1) val = (float)tok;
        else if (j == 2) val = (float)k;
        else if (j == 3) val = (float)(d / MT); // recover expert id
        else if (j == 4) val = w8[k];
        meta[(long long)d * ML + j] = val;
    }
}

// ---------------------------------------------------------------------------
// K5: fill unused slots — dispatched rows -> 0, metadata rows -> -1.
// d_out is poisoned 0xAA before every timed launch, so every byte must be
// written each call. One block per (expert, row); written rows early-exit.
__global__ void fill_kernel(const int* __restrict__ tokens_total,
                            float* __restrict__ out) {
    const int b = blockIdx.x;  // e*MT + r
    const int e = b / MT;
    const int r = b - e * MT;
    if (r < tokens_total[e]) return;
    const int t = threadIdx.x;
    float4* o4 = (float4*)out;
    o4[(long long)b * (H / 4) + t] = make_float4(0.f, 0.f, 0.f, 0.f);
    if (t < ML) {
        float* meta = out + DISP_ELEMS;
        meta[(long long)b * ML + t] = -1.0f;
    }
}

// ---------------------------------------------------------------------------
extern "C" void kernel_launch(void* const* d_in, const int* in_sizes, int n_in,
                              void* d_out, int out_size, void* d_ws, size_t ws_size,
                              hipStream_t stream) {
    const float* x  = (const float*)d_in[0];   // (C,S,H) f32
    const float* w  = (const float*)d_in[1];   // (C,S,K) f32
    const int* idx  = (const int*)d_in[2];     // (C,S,K) i32
    float* out = (float*)d_out;

    // workspace layout (ints): seg_counts | seg_base | dest | tokens_total
    int* ws = (int*)d_ws;
    int* seg_counts   = ws;                              // C*NSEG*E = 32768
    int* seg_base     = ws + C * NSEG * E;               // 32768
    int* dest         = ws + 2 * C * NSEG * E;           // C*N = 131072
    int* tokens_total = ws + 2 * C * NSEG * E + C * N;   // 64

    float* tpe_out = out + DISP_ELEMS + META_ELEMS;      // third output chunk

    hipLaunchKernelGGL(hist_kernel, dim3(C * NSEG), dim3(SEG), 0, stream, idx, seg_counts);
    hipLaunchKernelGGL(scan_kernel, dim3(1), dim3(E), 0, stream,
                       seg_counts, seg_base, tokens_total, tpe_out);
    hipLaunchKernelGGL(rank_kernel, dim3(C * NSEG), dim3(SEG), 0, stream, idx, seg_base, dest);
    hipLaunchKernelGGL(scatter_kernel, dim3(C * S), dim3(256), 0, stream, x, w, dest, out);
    hipLaunchKernelGGL(fill_kernel, dim3(E * MT), dim3(256), 0, stream, tokens_total, out);
}